// Round 13
// baseline (1711.559 us; speedup 1.0000x reference)
//
#include <hip/hip_runtime.h>
#include <math.h>

#define NB 759
#define NPT 220
#define KNN 10
#define XCCH 256
#define LDXC (XCCH * NPT)
#define KP 72

typedef float f4 __attribute__((ext_vector_type(4)));
typedef float f16v __attribute__((ext_vector_type(16)));
typedef short bf8v __attribute__((ext_vector_type(8)));   // 8 bf16 in 4 VGPRs
typedef unsigned u4v __attribute__((ext_vector_type(4))); // 16B copy unit

// ---- bf16 split helpers (RNE). h+m+l reconstructs fp32 ~exactly (24=3x8 bits).
__device__ inline unsigned short bfh(float x) {
  unsigned u = __float_as_uint(x);
  unsigned r = u + 0x7FFFu + ((u >> 16) & 1u);
  return (unsigned short)(r >> 16);
}
__device__ inline float bff(unsigned short h) {
  return __uint_as_float(((unsigned)h) << 16);
}
__device__ inline void bfsplit(float x, unsigned short& h, unsigned short& l) {
  h = bfh(x);
  l = bfh(x - bff(h));
}

// input (B,N,3) -> x0 (B,3,N)
__global__ __launch_bounds__(256) void k_transpose(const float* __restrict__ in, float* __restrict__ x0) {
  int i = blockIdx.x * 256 + threadIdx.x;
  if (i >= NB * 3 * NPT) return;
  int n = i % NPT; int t = i / NPT; int c = t % 3; int b = t / 3;
  x0[i] = in[(b * NPT + n) * 3 + c];
}

// W5 (512x256 fp32) -> Wh, Wl (bf16)
__global__ __launch_bounds__(256) void k_w5split(const float* __restrict__ W5,
    unsigned short* __restrict__ Wh, unsigned short* __restrict__ Wl) {
  int i = blockIdx.x * 256 + threadIdx.x;
  if (i >= 512 * 256) return;
  bfsplit(W5[i], Wh[i], Wl[i]);
}

__device__ inline void topk_insert(float d, int m, float* tv, int* ti) {
  if (d > tv[KNN - 1]) {      // strict >: ties keep earlier index (matches lax.top_k set)
    tv[KNN - 1] = d; ti[KNN - 1] = m;
    #pragma unroll
    for (int j = KNN - 1; j >= 1; --j) {
      if (tv[j] > tv[j - 1]) {
        float tf = tv[j - 1]; tv[j - 1] = tv[j]; tv[j] = tf;
        int tq = ti[j - 1]; ti[j - 1] = ti[j]; ti[j] = tq;
      } else break;
    }
  }
}

// kNN for C=3: cheap VALU version
__global__ __launch_bounds__(256) void k_knn3(const float* __restrict__ x, int ldb,
                                              int* __restrict__ idxout) {
  __shared__ __align__(16) float xl[NPT * 4];
  __shared__ float xx[NPT];
  int b = blockIdx.x;
  const float* xb = x + (size_t)b * ldb;
  for (int i = threadIdx.x; i < NPT; i += 256) {
    f4 v; v.x = xb[i]; v.y = xb[NPT + i]; v.z = xb[2 * NPT + i]; v.w = 0.f;
    *(f4*)&xl[i * 4] = v;
    xx[i] = v.x * v.x + v.y * v.y + v.z * v.z;
  }
  __syncthreads();
  int n = threadIdx.x;
  if (n >= NPT) return;
  f4 xn = *(const f4*)&xl[n * 4];
  float xxn = xx[n];
  float tv[KNN]; int ti[KNN];
  #pragma unroll
  for (int k = 0; k < KNN; ++k) { tv[k] = -1e30f; ti[k] = 0; }
  for (int m = 0; m < NPT; ++m) {
    f4 v = *(const f4*)&xl[m * 4];
    float dot = xn.x * v.x + xn.y * v.y + xn.z * v.z;
    topk_insert(2.f * dot - xxn - xx[m], m, tv, ti);
  }
  int* ib = idxout + ((size_t)b * NPT + n) * KNN;
  #pragma unroll
  for (int k = 0; k < KNN; ++k) ib[k] = ti[k];
}

// kNN via MFMA Gram matrix, 3-way bf16 split (6 products ~ fp32-exact).
template<int C>
__global__ __launch_bounds__(512) void k_knn_mfma(const float* __restrict__ x, int ldb,
                                                  int* __restrict__ idxout) {
  constexpr int KPG = C + 8;
  constexpr int SW = (C / 16) - 1;
  __shared__ __align__(16) unsigned short XH[224 * KPG];
  __shared__ __align__(16) unsigned short XM[224 * KPG];
  __shared__ __align__(16) unsigned short XL[224 * KPG];
  __shared__ float xx[224];
  int b = blockIdx.x;
  const float* xb = x + (size_t)b * ldb;
  for (int i = threadIdx.x; i < C * 224; i += 512) {
    int c = i / 224, m = i - c * 224;
    float v = (m < NPT) ? xb[c * NPT + m] : 0.f;
    unsigned short h = bfh(v);
    float r1 = v - bff(h);
    unsigned short mm = bfh(r1);
    unsigned short l = bfh(r1 - bff(mm));
    int cs = c ^ ((m & SW) << 4);
    XH[m * KPG + cs] = h; XM[m * KPG + cs] = mm; XL[m * KPG + cs] = l;
  }
  for (int m = threadIdx.x; m < 224; m += 512) {
    float s = 0.f;
    if (m < NPT) {
      for (int c = 0; c < C; ++c) { float v = xb[c * NPT + m]; s += v * v; }
    } else s = 1e30f;
    xx[m] = s;
  }
  __syncthreads();
  int w = threadIdx.x >> 6;
  int lane = threadIdx.x & 63;
  int lc = lane & 31, hi = lane >> 5;
  float tv[KNN]; int ti[KNN];
  #pragma unroll
  for (int k = 0; k < KNN; ++k) { tv[k] = -1e30f; ti[k] = 0; }
  if (w < 7) {
    int n = w * 32 + lc;
    f16v acc[7];
    #pragma unroll
    for (int mt = 0; mt < 7; ++mt)
      #pragma unroll
      for (int i = 0; i < 16; ++i) acc[mt][i] = 0.f;
    #pragma unroll
    for (int ks = 0; ks < C / 16; ++ks) {
      int kb = ks * 16 + hi * 8;
      int nsw = kb ^ ((n & SW) << 4);
      bf8v bh = *(const bf8v*)&XH[n * KPG + nsw];
      bf8v bm = *(const bf8v*)&XM[n * KPG + nsw];
      bf8v bl = *(const bf8v*)&XL[n * KPG + nsw];
      #pragma unroll
      for (int mt = 0; mt < 7; ++mt) {
        int mr = mt * 32 + lc;
        int msw = kb ^ ((mr & SW) << 4);
        bf8v ah = *(const bf8v*)&XH[mr * KPG + msw];
        bf8v am = *(const bf8v*)&XM[mr * KPG + msw];
        bf8v al = *(const bf8v*)&XL[mr * KPG + msw];
        acc[mt] = __builtin_amdgcn_mfma_f32_32x32x16_bf16(ah, bh, acc[mt], 0, 0, 0);
        acc[mt] = __builtin_amdgcn_mfma_f32_32x32x16_bf16(am, bh, acc[mt], 0, 0, 0);
        acc[mt] = __builtin_amdgcn_mfma_f32_32x32x16_bf16(ah, bm, acc[mt], 0, 0, 0);
        acc[mt] = __builtin_amdgcn_mfma_f32_32x32x16_bf16(am, bm, acc[mt], 0, 0, 0);
        acc[mt] = __builtin_amdgcn_mfma_f32_32x32x16_bf16(al, bh, acc[mt], 0, 0, 0);
        acc[mt] = __builtin_amdgcn_mfma_f32_32x32x16_bf16(ah, bl, acc[mt], 0, 0, 0);
      }
    }
    float xxn = xx[n];
    #pragma unroll
    for (int mt = 0; mt < 7; ++mt)
      #pragma unroll
      for (int i = 0; i < 16; ++i) {
        int m = mt * 32 + (i & 3) + 8 * (i >> 2) + 4 * hi;
        float d = 2.f * acc[mt][i] - xx[m] - xxn;
        topk_insert(d, m, tv, ti);
      }
  }
  __syncthreads();
  float* LV = (float*)XH;
  int* LI = (int*)XM;
  if (w < 7) {
    int slot = (w * 64 + lane) * KNN;
    #pragma unroll
    for (int k = 0; k < KNN; ++k) { LV[slot + k] = tv[k]; LI[slot + k] = ti[k]; }
  }
  __syncthreads();
  if (w < 7 && hi == 0) {
    int n = w * 32 + lc;
    if (n < NPT) {
      int sa = (w * 64 + lane) * KNN, sb = sa + 32 * KNN;
      int a = 0, bq = 0;
      int* ob = idxout + ((size_t)b * NPT + n) * KNN;
      #pragma unroll
      for (int k = 0; k < KNN; ++k) {
        float va = LV[sa + a], vb = LV[sb + bq];
        int ia = LI[sa + a], ic = LI[sb + bq];
        bool ta = (va > vb) || (va == vb && ia < ic);
        ob[k] = ta ? ia : ic;
        if (ta) ++a; else ++bq;
      }
    }
  }
}

// Fused edge conv — 512 threads. WBF16: for channels c>=csplit, also emit h/l
// bf16 in the w5 LDS-image layout [b][chunk64][n224][KP], so w5 staging is a
// contiguous memcpy. h/l bits identical to fallback's (same v, same bfsplit).
template<int CIN, int OG, bool WBF16, bool WF32>
__global__ __launch_bounds__(512, 4) void k_conv_fused(const float* __restrict__ x, int ldb,
    const float* __restrict__ W, const int* __restrict__ idxb, float* __restrict__ xout, int ldo,
    unsigned short* __restrict__ xch, unsigned short* __restrict__ xcl, int cbase,
    int csplit, int nch) {
  constexpr int NPAD = 224;
  constexpr int DBS = 224;
  constexpr int REGION = 64 * DBS;
  __shared__ __align__(16) float smem[REGION + CIN * 64];
  __shared__ unsigned short idxl[NPT * KNN];
  float* xl = smem;
  float* db = smem;
  float* wl = smem + REGION;
  int d = blockIdx.x;
  int b, og;
  if (OG == 4)      { b = (d & 7) * 95 + (d >> 5); og = (d >> 3) & 3; }
  else if (OG == 2) { b = (d & 7) * 95 + (d >> 4); og = (d >> 3) & 1; }
  else              { b = d; og = 0; }
  if (b >= NB) return;
  const float* xb = x + (size_t)b * ldb;
  for (int i = threadIdx.x; i < CIN * NPAD; i += 512) {
    int c = i / NPAD, n = i - c * NPAD;
    xl[i] = (n < NPT) ? xb[c * NPT + n] : 0.f;
  }
  for (int i = threadIdx.x; i < 64 * CIN; i += 512) {
    int rl = i & 63, c = i >> 6;
    int o = og * 32 + (rl & 31);
    float wv = (rl < 32) ? W[o * 2 * CIN + c]
                         : (W[o * 2 * CIN + CIN + c] - W[o * 2 * CIN + c]);
    wl[c * 64 + rl] = wv;
  }
  for (int i = threadIdx.x; i < NPT * KNN; i += 512)
    idxl[i] = (unsigned short)idxb[(size_t)b * NPT * KNN + i];
  __syncthreads();
  int rq = threadIdx.x & 15, nq = threadIdx.x >> 4;   // nq in [0,32)
  int gv[2]; bool gok[2];
  #pragma unroll
  for (int j = 0; j < 2; ++j) { int g = nq + j * 32; gok[j] = g < 55; gv[j] = (g < 55 ? g : 54) * 4; }
  f4 acc[2][4];
  #pragma unroll
  for (int j = 0; j < 2; ++j)
    #pragma unroll
    for (int i2 = 0; i2 < 4; ++i2) acc[j][i2] = (f4){0.f, 0.f, 0.f, 0.f};
  #pragma unroll 2
  for (int c = 0; c < CIN; ++c) {
    f4 wv = *(const f4*)&wl[c * 64 + rq * 4];
    #pragma unroll
    for (int j = 0; j < 2; ++j) {
      f4 xv = *(const f4*)&xl[c * NPAD + gv[j]];
      acc[j][0] += wv.x * xv; acc[j][1] += wv.y * xv;
      acc[j][2] += wv.z * xv; acc[j][3] += wv.w * xv;
    }
  }
  __syncthreads();
  #pragma unroll
  for (int j = 0; j < 2; ++j) {
    if (gok[j]) {
      #pragma unroll
      for (int i2 = 0; i2 < 4; ++i2)
        *(f4*)&db[(rq * 4 + i2) * DBS + gv[j]] = acc[j][i2];
    }
  }
  __syncthreads();
  int o0 = og * 32;
  for (int i = threadIdx.x; i < 32 * 224; i += 512) {
    int ol = i / 224, n = i - ol * 224;
    unsigned short h = 0, l = 0;
    if (n < NPT) {
      const float* drow = &db[ol * DBS];
      const unsigned short* ib = &idxl[n * KNN];
      float mx = -1e30f;
      #pragma unroll
      for (int k = 0; k < KNN; ++k) mx = fmaxf(mx, drow[ib[k]]);
      float v = mx + db[(32 + ol) * DBS + n];
      v = (v >= 0.f) ? v : 0.2f * v;
      if (WF32) xout[((size_t)b * ldo + o0 + ol) * NPT + n] = v;
      if (WBF16) bfsplit(v, h, l);
    }
    if (WBF16) {
      int c = cbase + o0 + ol;
      if (c >= csplit) {
        int cc = c - csplit;
        size_t off = (((size_t)b * nch + (cc >> 6)) * 224 + n) * (size_t)KP + (cc & 63);
        xch[off] = h;
        xcl[off] = l;
      }
    }
  }
}

// W5 GEMM via split-bf16 MFMA (R6 structure). Hybrid staging: chunks
// cb < split_cb split inline from fp32 xc; cb >= split_cb are contiguous
// memcpys from the conv-emitted h/l image. split_cb=4 == exact fallback.
__global__ __launch_bounds__(256) void k_w5_mfma(const float* __restrict__ xc, int chs,
    const unsigned short* __restrict__ xh, const unsigned short* __restrict__ xlo,
    int split_cb, int nch,
    const unsigned short* __restrict__ Wh, const unsigned short* __restrict__ Wl,
    const float* __restrict__ g5, const float* __restrict__ b5, const float* __restrict__ m5,
    const float* __restrict__ v5, float* __restrict__ p) {
  __shared__ __align__(16) unsigned short XH[224 * KP];
  __shared__ __align__(16) unsigned short XL[224 * KP];
  int d = blockIdx.x;
  int b = (d & 7) * 95 + (d >> 5);
  int rg = (d >> 3) & 3;
  if (b >= NB) return;
  int lane = threadIdx.x & 63, w = threadIdx.x >> 6;
  f16v acc[7];
  #pragma unroll
  for (int t = 0; t < 7; ++t)
    #pragma unroll
    for (int i = 0; i < 16; ++i) acc[t][i] = 0.f;

  int r = rg * 128 + w * 32 + (lane & 31);
  int khalf = (lane >> 5) * 8;

  for (int cb = 0; cb < 4; ++cb) {
    if (cb) __syncthreads();
    if (cb < split_cb) {
      // inline split from fp32 xc (identical to fallback)
      for (int i = threadIdx.x; i < 32 * NPT; i += 256) {
        int cp = i / NPT;
        int n = i - cp * NPT;
        int c0 = cp * 2;
        const float* src = &xc[((size_t)b * chs + cb * 64 + c0) * NPT + n];
        float x0 = src[0];
        float x1 = src[NPT];
        unsigned short h0, l0, h1, l1;
        bfsplit(x0, h0, l0); bfsplit(x1, h1, l1);
        ((unsigned*)XH)[(n * KP + c0) >> 1] = (unsigned)h0 | ((unsigned)h1 << 16);
        ((unsigned*)XL)[(n * KP + c0) >> 1] = (unsigned)l0 | ((unsigned)l1 << 16);
      }
      for (int i = threadIdx.x; i < 4 * 32; i += 256) {
        int n = NPT + (i >> 5); int cd = i & 31;
        ((unsigned*)XH)[n * (KP / 2) + cd] = 0u;
        ((unsigned*)XL)[n * (KP / 2) + cd] = 0u;
      }
    } else {
      // contiguous memcpy: global layout == LDS layout [224][KP]
      int q = cb - split_cb;
      const u4v* sH = (const u4v*)(xh + (((size_t)b * nch + q) * 224) * KP);
      const u4v* sL = (const u4v*)(xlo + (((size_t)b * nch + q) * 224) * KP);
      u4v* dH = (u4v*)XH;
      u4v* dL = (u4v*)XL;
      for (int i = threadIdx.x; i < 224 * KP / 8; i += 256) {
        dH[i] = sH[i];
        dL[i] = sL[i];
      }
    }
    __syncthreads();
    #pragma unroll
    for (int ks = 0; ks < 4; ++ks) {
      int kg = cb * 64 + ks * 16 + khalf;
      int kl = ks * 16 + khalf;
      bf8v ah = *(const bf8v*)&Wh[(size_t)r * 256 + kg];
      bf8v al = *(const bf8v*)&Wl[(size_t)r * 256 + kg];
      #pragma unroll
      for (int t = 0; t < 7; ++t) {
        int col = t * 32 + (lane & 31);
        bf8v bh = *(const bf8v*)&XH[col * KP + kl];
        bf8v bl = *(const bf8v*)&XL[col * KP + kl];
        acc[t] = __builtin_amdgcn_mfma_f32_32x32x16_bf16(ah, bh, acc[t], 0, 0, 0);
        acc[t] = __builtin_amdgcn_mfma_f32_32x32x16_bf16(al, bh, acc[t], 0, 0, 0);
        acc[t] = __builtin_amdgcn_mfma_f32_32x32x16_bf16(ah, bl, acc[t], 0, 0, 0);
      }
    }
  }
  int rbase = rg * 128 + w * 32 + 4 * (lane >> 5);
  int lc = lane & 31;
  #pragma unroll
  for (int i = 0; i < 16; ++i) {
    int row = rbase + (i & 3) + 8 * (i >> 2);
    float a = g5[row] * rsqrtf(v5[row] + 1e-5f);
    float dq = b5[row] - m5[row] * a;
    float mx = -1e30f, sm = 0.f;
    #pragma unroll
    for (int t = 0; t < 7; ++t) {
      bool valid = (t < 6) || (lc < 28);
      float hv = a * acc[t][i] + dq;
      float lv = (hv >= 0.f) ? hv : 0.2f * hv;
      if (valid) { mx = fmaxf(mx, lv); sm += lv; }
    }
    #pragma unroll
    for (int m_ = 1; m_ <= 16; m_ <<= 1) {
      mx = fmaxf(mx, __shfl_xor(mx, m_));
      sm += __shfl_xor(sm, m_);
    }
    if (lc == 0) {
      p[(size_t)b * 1024 + row] = mx;
      p[(size_t)b * 1024 + 512 + row] = sm * (1.f / NPT);
    }
  }
}

// out[b][o] = in[b][:] . Wt[o][:]  (+ bn+leaky | + bias)
template<int ON, bool FUSE>
__global__ __launch_bounds__(256) void k_fc(const float* __restrict__ in, const float* __restrict__ Wt,
    const float* __restrict__ q0, const float* __restrict__ q1, const float* __restrict__ q2,
    const float* __restrict__ q3, float* __restrict__ out, int ostride) {
  __shared__ __align__(16) float il[32 * 68];
  __shared__ __align__(16) float wl[32 * 68];
  int b0 = blockIdx.x * 64, o0 = blockIdx.y * 64;
  int oq = threadIdx.x & 15, bq = threadIdx.x >> 4;
  f4 acc[4];
  #pragma unroll
  for (int i2 = 0; i2 < 4; ++i2) acc[i2] = (f4){0.f, 0.f, 0.f, 0.f};
  for (int cb = 0; cb < 32; ++cb) {
    if (cb) __syncthreads();
    for (int i = threadIdx.x; i < 2048; i += 256) {
      int c = i & 31, bb = i >> 5;
      il[c * 68 + bb] = (b0 + bb < NB) ? in[(b0 + bb) * 1024 + cb * 32 + c] : 0.f;
    }
    for (int i = threadIdx.x; i < 2048; i += 256) {
      int c = i & 31, ol = i >> 5;
      wl[c * 68 + ol] = (o0 + ol < ON) ? Wt[(o0 + ol) * 1024 + cb * 32 + c] : 0.f;
    }
    __syncthreads();
    #pragma unroll
    for (int c = 0; c < 32; ++c) {
      f4 wv = *(const f4*)&wl[c * 68 + oq * 4];
      f4 iv = *(const f4*)&il[c * 68 + bq * 4];
      acc[0] += wv.x * iv; acc[1] += wv.y * iv; acc[2] += wv.z * iv; acc[3] += wv.w * iv;
    }
  }
  #pragma unroll
  for (int i2 = 0; i2 < 4; ++i2) {
    int o = o0 + oq * 4 + i2;
    if (o >= ON) continue;
    float A = 1.f, Dv = 0.f;
    if (FUSE) { float a = q0[o] * rsqrtf(q3[o] + 1e-5f); A = a; Dv = q1[o] - q2[o] * a; }
    else { Dv = q0[o]; }
    #pragma unroll
    for (int jj = 0; jj < 4; ++jj) {
      int bb = b0 + bq * 4 + jj;
      if (bb < NB) {
        float v = acc[i2][jj];
        if (FUSE) { v = A * v + Dv; v = (v >= 0.f) ? v : 0.2f * v; }
        else { v = v + Dv; }
        out[(size_t)bb * ostride + o] = v;
      }
    }
  }
}

extern "C" void kernel_launch(void* const* d_in, const int* in_sizes, int n_in,
                              void* d_out, int out_size, void* d_ws, size_t ws_size,
                              hipStream_t stream) {
  const float* input = (const float*)d_in[0];
  const float* W1 = (const float*)d_in[1];
  const float* W2 = (const float*)d_in[2];
  const float* W3 = (const float*)d_in[3];
  const float* W4 = (const float*)d_in[4];
  const float* W5 = (const float*)d_in[5];
  const float* g5 = (const float*)d_in[6];
  const float* b5 = (const float*)d_in[7];
  const float* m5 = (const float*)d_in[8];
  const float* v5 = (const float*)d_in[9];
  const float* Wl1 = (const float*)d_in[10];
  const float* g6 = (const float*)d_in[11];
  const float* b6 = (const float*)d_in[12];
  const float* m6 = (const float*)d_in[13];
  const float* v6 = (const float*)d_in[14];
  const float* Wl2 = (const float*)d_in[15];
  const float* bl2 = (const float*)d_in[16];

  float* w = (float*)d_ws;
  // Tiered layouts. Per-64ch h/l chunk: 759*224*72 = 12,241,152 shorts each of
  // h and l -> 12,241,152 float-equivalents per chunk for the pair.
  // need(NCH) = 4*(25,229,684 + 12,241,152*NCH) bytes.
  int NCH = 0;
  if (ws_size >= 4ull * (25229684ull + 12241152ull * 3)) NCH = 3;       // x3+x4 pre-split, 247.9 MB
  else if (ws_size >= 4ull * (25229684ull + 12241152ull * 2)) NCH = 2;  // x4 pre-split, 198.9 MB

  float *x0, *xc, *p, *z; int* idxb;
  unsigned short *wh, *wlo, *xh, *xlo;
  int chs, csplit, split_cb;
  if (NCH > 0) {
    x0 = w;                               //      500,940
    xc = x0 + 500940;                     //   21,373,440 (759*128*220 fp32: x1|x2|x3)
    p  = xc + 21373440;                   //      777,216
    z  = p  + 777216;                     //      777,216
    idxb = (int*)(z + 777216);            //    1,669,800 ints
    wh  = (unsigned short*)(w + 25098612);
    wlo = wh + 131072;
    xh  = wlo + 131072;                   //   NCH*12,241,152 shorts
    xlo = xh + (size_t)NCH * 12241152;
    chs = 128; csplit = 256 - 64 * NCH; split_cb = 4 - NCH;
  } else {
    x0 = w;
    xc = x0 + 500940;                     //   42,746,880 (759*256*220 fp32)
    p  = xc + 42746880;
    z  = p  + 777216;
    idxb = (int*)(z + 777216);
    wh  = (unsigned short*)(w + 46472052);
    wlo = wh + 131072;
    xh = wlo; xlo = wlo;                  // unused
    chs = 256; csplit = 256; split_cb = 4;
  }
  int ldxc = chs * NPT;

  k_transpose<<<1957, 256, 0, stream>>>(input, x0);
  k_w5split<<<512, 256, 0, stream>>>(W5, wh, wlo);

  k_knn3<<<759, 256, 0, stream>>>(x0, 3 * NPT, idxb);

  if (NCH == 3) {
    k_conv_fused<3, 1, false, true><<<759, 512, 0, stream>>>(x0, 3 * NPT, W1, idxb, xc, chs, xh, xlo, 0, csplit, NCH);
    k_knn_mfma<32><<<759, 512, 0, stream>>>(xc, ldxc, idxb);
    k_conv_fused<32, 1, false, true><<<759, 512, 0, stream>>>(xc, ldxc, W2, idxb, xc + 32 * NPT, chs, xh, xlo, 32, csplit, NCH);
    k_knn_mfma<32><<<759, 512, 0, stream>>>(xc + 32 * NPT, ldxc, idxb);
    k_conv_fused<32, 2, true, true><<<1520, 512, 0, stream>>>(xc + 32 * NPT, ldxc, W3, idxb, xc + 64 * NPT, chs, xh, xlo, 64, csplit, NCH);
    k_knn_mfma<64><<<759, 512, 0, stream>>>(xc + 64 * NPT, ldxc, idxb);
    k_conv_fused<64, 4, true, false><<<3040, 512, 0, stream>>>(xc + 64 * NPT, ldxc, W4, idxb, xc, 0, xh, xlo, 128, csplit, NCH);
  } else if (NCH == 2) {
    k_conv_fused<3, 1, false, true><<<759, 512, 0, stream>>>(x0, 3 * NPT, W1, idxb, xc, chs, xh, xlo, 0, csplit, NCH);
    k_knn_mfma<32><<<759, 512, 0, stream>>>(xc, ldxc, idxb);
    k_conv_fused<32, 1, false, true><<<759, 512, 0, stream>>>(xc, ldxc, W2, idxb, xc + 32 * NPT, chs, xh, xlo, 32, csplit, NCH);
    k_knn_mfma<32><<<759, 512, 0, stream>>>(xc + 32 * NPT, ldxc, idxb);
    k_conv_fused<32, 2, false, true><<<1520, 512, 0, stream>>>(xc + 32 * NPT, ldxc, W3, idxb, xc + 64 * NPT, chs, xh, xlo, 64, csplit, NCH);
    k_knn_mfma<64><<<759, 512, 0, stream>>>(xc + 64 * NPT, ldxc, idxb);
    k_conv_fused<64, 4, true, false><<<3040, 512, 0, stream>>>(xc + 64 * NPT, ldxc, W4, idxb, xc, 0, xh, xlo, 128, csplit, NCH);
  } else {
    k_conv_fused<3, 1, false, true><<<759, 512, 0, stream>>>(x0, 3 * NPT, W1, idxb, xc, chs, xh, xlo, 0, csplit, NCH);
    k_knn_mfma<32><<<759, 512, 0, stream>>>(xc, ldxc, idxb);
    k_conv_fused<32, 1, false, true><<<759, 512, 0, stream>>>(xc, ldxc, W2, idxb, xc + 32 * NPT, chs, xh, xlo, 32, csplit, NCH);
    k_knn_mfma<32><<<759, 512, 0, stream>>>(xc + 32 * NPT, ldxc, idxb);
    k_conv_fused<32, 2, false, true><<<1520, 512, 0, stream>>>(xc + 32 * NPT, ldxc, W3, idxb, xc + 64 * NPT, chs, xh, xlo, 64, csplit, NCH);
    k_knn_mfma<64><<<759, 512, 0, stream>>>(xc + 64 * NPT, ldxc, idxb);
    k_conv_fused<64, 4, false, true><<<3040, 512, 0, stream>>>(xc + 64 * NPT, ldxc, W4, idxb, xc + 128 * NPT, chs, xh, xlo, 128, csplit, NCH);
  }

  k_w5_mfma<<<3040, 256, 0, stream>>>(xc, chs, xh, xlo, split_cb, NCH, wh, wlo, g5, b5, m5, v5, p);

  k_fc<1024, true><<<dim3(12, 16), 256, 0, stream>>>(p, Wl1, g6, b6, m6, v6, z, 1024);
  k_fc<380, false><<<dim3(12, 6), 256, 0, stream>>>(z, Wl2, bl2, bl2, bl2, bl2, (float*)d_out, 380);
}

// Round 14
// 1578.476 us; speedup vs baseline: 1.0843x; 1.0843x over previous
//
#include <hip/hip_runtime.h>
#include <math.h>

#define NB 759
#define NPT 220
#define KNN 10
#define XCCH 256
#define LDXC (XCCH * NPT)
#define KP 72

typedef float f4 __attribute__((ext_vector_type(4)));
typedef float f16v __attribute__((ext_vector_type(16)));
typedef short bf8v __attribute__((ext_vector_type(8)));   // 8 bf16 in 4 VGPRs
typedef unsigned u4v __attribute__((ext_vector_type(4))); // 16B copy unit

// ---- bf16 split helpers (RNE). h+m+l reconstructs fp32 ~exactly (24=3x8 bits).
__device__ inline unsigned short bfh(float x) {
  unsigned u = __float_as_uint(x);
  unsigned r = u + 0x7FFFu + ((u >> 16) & 1u);
  return (unsigned short)(r >> 16);
}
__device__ inline float bff(unsigned short h) {
  return __uint_as_float(((unsigned)h) << 16);
}
__device__ inline void bfsplit(float x, unsigned short& h, unsigned short& l) {
  h = bfh(x);
  l = bfh(x - bff(h));
}

// input (B,N,3) -> x0 (B,3,N)
__global__ __launch_bounds__(256) void k_transpose(const float* __restrict__ in, float* __restrict__ x0) {
  int i = blockIdx.x * 256 + threadIdx.x;
  if (i >= NB * 3 * NPT) return;
  int n = i % NPT; int t = i / NPT; int c = t % 3; int b = t / 3;
  x0[i] = in[(b * NPT + n) * 3 + c];
}

// W5 (512x256 fp32) -> Wh, Wl (bf16)
__global__ __launch_bounds__(256) void k_w5split(const float* __restrict__ W5,
    unsigned short* __restrict__ Wh, unsigned short* __restrict__ Wl) {
  int i = blockIdx.x * 256 + threadIdx.x;
  if (i >= 512 * 256) return;
  bfsplit(W5[i], Wh[i], Wl[i]);
}

__device__ inline void topk_insert(float d, int m, float* tv, int* ti) {
  if (d > tv[KNN - 1]) {      // strict >: ties keep earlier index (matches lax.top_k set)
    tv[KNN - 1] = d; ti[KNN - 1] = m;
    #pragma unroll
    for (int j = KNN - 1; j >= 1; --j) {
      if (tv[j] > tv[j - 1]) {
        float tf = tv[j - 1]; tv[j - 1] = tv[j]; tv[j] = tf;
        int tq = ti[j - 1]; ti[j - 1] = ti[j]; ti[j] = tq;
      } else break;
    }
  }
}

// kNN for C=3: cheap VALU version
__global__ __launch_bounds__(256) void k_knn3(const float* __restrict__ x, int ldb,
                                              int* __restrict__ idxout) {
  __shared__ __align__(16) float xl[NPT * 4];
  __shared__ float xx[NPT];
  int b = blockIdx.x;
  const float* xb = x + (size_t)b * ldb;
  for (int i = threadIdx.x; i < NPT; i += 256) {
    f4 v; v.x = xb[i]; v.y = xb[NPT + i]; v.z = xb[2 * NPT + i]; v.w = 0.f;
    *(f4*)&xl[i * 4] = v;
    xx[i] = v.x * v.x + v.y * v.y + v.z * v.z;
  }
  __syncthreads();
  int n = threadIdx.x;
  if (n >= NPT) return;
  f4 xn = *(const f4*)&xl[n * 4];
  float xxn = xx[n];
  float tv[KNN]; int ti[KNN];
  #pragma unroll
  for (int k = 0; k < KNN; ++k) { tv[k] = -1e30f; ti[k] = 0; }
  for (int m = 0; m < NPT; ++m) {
    f4 v = *(const f4*)&xl[m * 4];
    float dot = xn.x * v.x + xn.y * v.y + xn.z * v.z;
    topk_insert(2.f * dot - xxn - xx[m], m, tv, ti);
  }
  int* ib = idxout + ((size_t)b * NPT + n) * KNN;
  #pragma unroll
  for (int k = 0; k < KNN; ++k) ib[k] = ti[k];
}

// kNN via MFMA Gram matrix, 3-way bf16 split (6 products ~ fp32-exact).
template<int C>
__global__ __launch_bounds__(512) void k_knn_mfma(const float* __restrict__ x, int ldb,
                                                  int* __restrict__ idxout) {
  constexpr int KPG = C + 8;
  constexpr int SW = (C / 16) - 1;
  __shared__ __align__(16) unsigned short XH[224 * KPG];
  __shared__ __align__(16) unsigned short XM[224 * KPG];
  __shared__ __align__(16) unsigned short XL[224 * KPG];
  __shared__ float xx[224];
  int b = blockIdx.x;
  const float* xb = x + (size_t)b * ldb;
  for (int i = threadIdx.x; i < C * 224; i += 512) {
    int c = i / 224, m = i - c * 224;
    float v = (m < NPT) ? xb[c * NPT + m] : 0.f;
    unsigned short h = bfh(v);
    float r1 = v - bff(h);
    unsigned short mm = bfh(r1);
    unsigned short l = bfh(r1 - bff(mm));
    int cs = c ^ ((m & SW) << 4);
    XH[m * KPG + cs] = h; XM[m * KPG + cs] = mm; XL[m * KPG + cs] = l;
  }
  for (int m = threadIdx.x; m < 224; m += 512) {
    float s = 0.f;
    if (m < NPT) {
      for (int c = 0; c < C; ++c) { float v = xb[c * NPT + m]; s += v * v; }
    } else s = 1e30f;
    xx[m] = s;
  }
  __syncthreads();
  int w = threadIdx.x >> 6;
  int lane = threadIdx.x & 63;
  int lc = lane & 31, hi = lane >> 5;
  float tv[KNN]; int ti[KNN];
  #pragma unroll
  for (int k = 0; k < KNN; ++k) { tv[k] = -1e30f; ti[k] = 0; }
  if (w < 7) {
    int n = w * 32 + lc;
    f16v acc[7];
    #pragma unroll
    for (int mt = 0; mt < 7; ++mt)
      #pragma unroll
      for (int i = 0; i < 16; ++i) acc[mt][i] = 0.f;
    #pragma unroll
    for (int ks = 0; ks < C / 16; ++ks) {
      int kb = ks * 16 + hi * 8;
      int nsw = kb ^ ((n & SW) << 4);
      bf8v bh = *(const bf8v*)&XH[n * KPG + nsw];
      bf8v bm = *(const bf8v*)&XM[n * KPG + nsw];
      bf8v bl = *(const bf8v*)&XL[n * KPG + nsw];
      #pragma unroll
      for (int mt = 0; mt < 7; ++mt) {
        int mr = mt * 32 + lc;
        int msw = kb ^ ((mr & SW) << 4);
        bf8v ah = *(const bf8v*)&XH[mr * KPG + msw];
        bf8v am = *(const bf8v*)&XM[mr * KPG + msw];
        bf8v al = *(const bf8v*)&XL[mr * KPG + msw];
        acc[mt] = __builtin_amdgcn_mfma_f32_32x32x16_bf16(ah, bh, acc[mt], 0, 0, 0);
        acc[mt] = __builtin_amdgcn_mfma_f32_32x32x16_bf16(am, bh, acc[mt], 0, 0, 0);
        acc[mt] = __builtin_amdgcn_mfma_f32_32x32x16_bf16(ah, bm, acc[mt], 0, 0, 0);
        acc[mt] = __builtin_amdgcn_mfma_f32_32x32x16_bf16(am, bm, acc[mt], 0, 0, 0);
        acc[mt] = __builtin_amdgcn_mfma_f32_32x32x16_bf16(al, bh, acc[mt], 0, 0, 0);
        acc[mt] = __builtin_amdgcn_mfma_f32_32x32x16_bf16(ah, bl, acc[mt], 0, 0, 0);
      }
    }
    float xxn = xx[n];
    #pragma unroll
    for (int mt = 0; mt < 7; ++mt)
      #pragma unroll
      for (int i = 0; i < 16; ++i) {
        int m = mt * 32 + (i & 3) + 8 * (i >> 2) + 4 * hi;
        float d = 2.f * acc[mt][i] - xx[m] - xxn;
        topk_insert(d, m, tv, ti);
      }
  }
  __syncthreads();
  float* LV = (float*)XH;
  int* LI = (int*)XM;
  if (w < 7) {
    int slot = (w * 64 + lane) * KNN;
    #pragma unroll
    for (int k = 0; k < KNN; ++k) { LV[slot + k] = tv[k]; LI[slot + k] = ti[k]; }
  }
  __syncthreads();
  if (w < 7 && hi == 0) {
    int n = w * 32 + lc;
    if (n < NPT) {
      int sa = (w * 64 + lane) * KNN, sb = sa + 32 * KNN;
      int a = 0, bq = 0;
      int* ob = idxout + ((size_t)b * NPT + n) * KNN;
      #pragma unroll
      for (int k = 0; k < KNN; ++k) {
        float va = LV[sa + a], vb = LV[sb + bq];
        int ia = LI[sa + a], ic = LI[sb + bq];
        bool ta = (va > vb) || (va == vb && ia < ic);
        ob[k] = ta ? ia : ic;
        if (ta) ++a; else ++bq;
      }
    }
  }
}

// Fused edge conv — 512 threads. R14: image (h/l) emission restructured to
// full-line stores: thread owns (n, channel-octet), 8 gathers share one idx
// load, packs 8 bf16 -> one 16B store; 4 lanes cover a 64B row segment ->
// waves write FULL lines (store transactions ~28x down vs R13 scatter).
// h/l bits identical to fallback (same v, same bfsplit).
template<int CIN, int OG, bool WBF16, bool WF32>
__global__ __launch_bounds__(512, 4) void k_conv_fused(const float* __restrict__ x, int ldb,
    const float* __restrict__ W, const int* __restrict__ idxb, float* __restrict__ xout, int ldo,
    unsigned short* __restrict__ xch, unsigned short* __restrict__ xcl, int cbase,
    int csplit, int nch) {
  constexpr int NPAD = 224;
  constexpr int DBS = 224;
  constexpr int REGION = 64 * DBS;
  __shared__ __align__(16) float smem[REGION + CIN * 64];
  __shared__ unsigned short idxl[NPT * KNN];
  float* xl = smem;
  float* db = smem;
  float* wl = smem + REGION;
  int d = blockIdx.x;
  int b, og;
  if (OG == 4)      { b = (d & 7) * 95 + (d >> 5); og = (d >> 3) & 3; }
  else if (OG == 2) { b = (d & 7) * 95 + (d >> 4); og = (d >> 3) & 1; }
  else              { b = d; og = 0; }
  if (b >= NB) return;
  const float* xb = x + (size_t)b * ldb;
  for (int i = threadIdx.x; i < CIN * NPAD; i += 512) {
    int c = i / NPAD, n = i - c * NPAD;
    xl[i] = (n < NPT) ? xb[c * NPT + n] : 0.f;
  }
  for (int i = threadIdx.x; i < 64 * CIN; i += 512) {
    int rl = i & 63, c = i >> 6;
    int o = og * 32 + (rl & 31);
    float wv = (rl < 32) ? W[o * 2 * CIN + c]
                         : (W[o * 2 * CIN + CIN + c] - W[o * 2 * CIN + c]);
    wl[c * 64 + rl] = wv;
  }
  for (int i = threadIdx.x; i < NPT * KNN; i += 512)
    idxl[i] = (unsigned short)idxb[(size_t)b * NPT * KNN + i];
  __syncthreads();
  int rq = threadIdx.x & 15, nq = threadIdx.x >> 4;   // nq in [0,32)
  int gv[2]; bool gok[2];
  #pragma unroll
  for (int j = 0; j < 2; ++j) { int g = nq + j * 32; gok[j] = g < 55; gv[j] = (g < 55 ? g : 54) * 4; }
  f4 acc[2][4];
  #pragma unroll
  for (int j = 0; j < 2; ++j)
    #pragma unroll
    for (int i2 = 0; i2 < 4; ++i2) acc[j][i2] = (f4){0.f, 0.f, 0.f, 0.f};
  #pragma unroll 2
  for (int c = 0; c < CIN; ++c) {
    f4 wv = *(const f4*)&wl[c * 64 + rq * 4];
    #pragma unroll
    for (int j = 0; j < 2; ++j) {
      f4 xv = *(const f4*)&xl[c * NPAD + gv[j]];
      acc[j][0] += wv.x * xv; acc[j][1] += wv.y * xv;
      acc[j][2] += wv.z * xv; acc[j][3] += wv.w * xv;
    }
  }
  __syncthreads();
  #pragma unroll
  for (int j = 0; j < 2; ++j) {
    if (gok[j]) {
      #pragma unroll
      for (int i2 = 0; i2 < 4; ++i2)
        *(f4*)&db[(rq * 4 + i2) * DBS + gv[j]] = acc[j][i2];
    }
  }
  __syncthreads();
  int o0 = og * 32;
  if (WF32) {
    for (int i = threadIdx.x; i < 32 * NPT; i += 512) {
      int ol = i / NPT, n = i - ol * NPT;
      const float* drow = &db[ol * DBS];
      const unsigned short* ib = &idxl[n * KNN];
      float mx = -1e30f;
      #pragma unroll
      for (int k = 0; k < KNN; ++k) mx = fmaxf(mx, drow[ib[k]]);
      float v = mx + db[(32 + ol) * DBS + n];
      v = (v >= 0.f) ? v : 0.2f * v;
      xout[((size_t)b * ldo + o0 + ol) * NPT + n] = v;
    }
  }
  if (WBF16) {
    // i = n*4 + cs: lanes (cs fastest) -> 4 lanes cover one 64B row segment
    for (int i = threadIdx.x; i < 224 * 4; i += 512) {
      int n = i >> 2, cs = i & 3;
      unsigned short hs[8], ls[8];
      if (n < NPT) {
        const unsigned short* ib = &idxl[n * KNN];
        unsigned short ixr[KNN];
        #pragma unroll
        for (int k = 0; k < KNN; ++k) ixr[k] = ib[k];
        #pragma unroll
        for (int j = 0; j < 8; ++j) {
          int ol = cs * 8 + j;
          const float* drow = &db[ol * DBS];
          float mx = -1e30f;
          #pragma unroll
          for (int k = 0; k < KNN; ++k) mx = fmaxf(mx, drow[ixr[k]]);
          float v = mx + db[(32 + ol) * DBS + n];
          v = (v >= 0.f) ? v : 0.2f * v;
          bfsplit(v, hs[j], ls[j]);
        }
      } else {
        #pragma unroll
        for (int j = 0; j < 8; ++j) { hs[j] = 0; ls[j] = 0; }
      }
      int cc0 = cbase + o0 + cs * 8 - csplit;
      size_t off = (((size_t)b * nch + (cc0 >> 6)) * 224 + n) * (size_t)KP + (cc0 & 63);
      u4v hv, lv;
      #pragma unroll
      for (int q = 0; q < 4; ++q) {
        hv[q] = (unsigned)hs[2 * q] | ((unsigned)hs[2 * q + 1] << 16);
        lv[q] = (unsigned)ls[2 * q] | ((unsigned)ls[2 * q + 1] << 16);
      }
      *(u4v*)&xch[off] = hv;
      *(u4v*)&xcl[off] = lv;
    }
  }
}

// W5 GEMM via split-bf16 MFMA (R6 structure). Hybrid staging: chunks
// cb < split_cb split inline from fp32 xc; cb >= split_cb are contiguous
// memcpys from the conv-emitted h/l image. split_cb=4 == exact fallback.
__global__ __launch_bounds__(256) void k_w5_mfma(const float* __restrict__ xc, int chs,
    const unsigned short* __restrict__ xh, const unsigned short* __restrict__ xlo,
    int split_cb, int nch,
    const unsigned short* __restrict__ Wh, const unsigned short* __restrict__ Wl,
    const float* __restrict__ g5, const float* __restrict__ b5, const float* __restrict__ m5,
    const float* __restrict__ v5, float* __restrict__ p) {
  __shared__ __align__(16) unsigned short XH[224 * KP];
  __shared__ __align__(16) unsigned short XL[224 * KP];
  int d = blockIdx.x;
  int b = (d & 7) * 95 + (d >> 5);
  int rg = (d >> 3) & 3;
  if (b >= NB) return;
  int lane = threadIdx.x & 63, w = threadIdx.x >> 6;
  f16v acc[7];
  #pragma unroll
  for (int t = 0; t < 7; ++t)
    #pragma unroll
    for (int i = 0; i < 16; ++i) acc[t][i] = 0.f;

  int r = rg * 128 + w * 32 + (lane & 31);
  int khalf = (lane >> 5) * 8;

  for (int cb = 0; cb < 4; ++cb) {
    if (cb) __syncthreads();
    if (cb < split_cb) {
      // inline split from fp32 xc (identical to fallback)
      for (int i = threadIdx.x; i < 32 * NPT; i += 256) {
        int cp = i / NPT;
        int n = i - cp * NPT;
        int c0 = cp * 2;
        const float* src = &xc[((size_t)b * chs + cb * 64 + c0) * NPT + n];
        float x0 = src[0];
        float x1 = src[NPT];
        unsigned short h0, l0, h1, l1;
        bfsplit(x0, h0, l0); bfsplit(x1, h1, l1);
        ((unsigned*)XH)[(n * KP + c0) >> 1] = (unsigned)h0 | ((unsigned)h1 << 16);
        ((unsigned*)XL)[(n * KP + c0) >> 1] = (unsigned)l0 | ((unsigned)l1 << 16);
      }
      for (int i = threadIdx.x; i < 4 * 32; i += 256) {
        int n = NPT + (i >> 5); int cd = i & 31;
        ((unsigned*)XH)[n * (KP / 2) + cd] = 0u;
        ((unsigned*)XL)[n * (KP / 2) + cd] = 0u;
      }
    } else {
      // contiguous memcpy: global layout == LDS layout [224][KP]
      int q = cb - split_cb;
      const u4v* sH = (const u4v*)(xh + (((size_t)b * nch + q) * 224) * KP);
      const u4v* sL = (const u4v*)(xlo + (((size_t)b * nch + q) * 224) * KP);
      u4v* dH = (u4v*)XH;
      u4v* dL = (u4v*)XL;
      for (int i = threadIdx.x; i < 224 * KP / 8; i += 256) {
        dH[i] = sH[i];
        dL[i] = sL[i];
      }
    }
    __syncthreads();
    #pragma unroll
    for (int ks = 0; ks < 4; ++ks) {
      int kg = cb * 64 + ks * 16 + khalf;
      int kl = ks * 16 + khalf;
      bf8v ah = *(const bf8v*)&Wh[(size_t)r * 256 + kg];
      bf8v al = *(const bf8v*)&Wl[(size_t)r * 256 + kg];
      #pragma unroll
      for (int t = 0; t < 7; ++t) {
        int col = t * 32 + (lane & 31);
        bf8v bh = *(const bf8v*)&XH[col * KP + kl];
        bf8v bl = *(const bf8v*)&XL[col * KP + kl];
        acc[t] = __builtin_amdgcn_mfma_f32_32x32x16_bf16(ah, bh, acc[t], 0, 0, 0);
        acc[t] = __builtin_amdgcn_mfma_f32_32x32x16_bf16(al, bh, acc[t], 0, 0, 0);
        acc[t] = __builtin_amdgcn_mfma_f32_32x32x16_bf16(ah, bl, acc[t], 0, 0, 0);
      }
    }
  }
  int rbase = rg * 128 + w * 32 + 4 * (lane >> 5);
  int lc = lane & 31;
  #pragma unroll
  for (int i = 0; i < 16; ++i) {
    int row = rbase + (i & 3) + 8 * (i >> 2);
    float a = g5[row] * rsqrtf(v5[row] + 1e-5f);
    float dq = b5[row] - m5[row] * a;
    float mx = -1e30f, sm = 0.f;
    #pragma unroll
    for (int t = 0; t < 7; ++t) {
      bool valid = (t < 6) || (lc < 28);
      float hv = a * acc[t][i] + dq;
      float lv = (hv >= 0.f) ? hv : 0.2f * hv;
      if (valid) { mx = fmaxf(mx, lv); sm += lv; }
    }
    #pragma unroll
    for (int m_ = 1; m_ <= 16; m_ <<= 1) {
      mx = fmaxf(mx, __shfl_xor(mx, m_));
      sm += __shfl_xor(sm, m_);
    }
    if (lc == 0) {
      p[(size_t)b * 1024 + row] = mx;
      p[(size_t)b * 1024 + 512 + row] = sm * (1.f / NPT);
    }
  }
}

// out[b][o] = in[b][:] . Wt[o][:]  (+ bn+leaky | + bias)
template<int ON, bool FUSE>
__global__ __launch_bounds__(256) void k_fc(const float* __restrict__ in, const float* __restrict__ Wt,
    const float* __restrict__ q0, const float* __restrict__ q1, const float* __restrict__ q2,
    const float* __restrict__ q3, float* __restrict__ out, int ostride) {
  __shared__ __align__(16) float il[32 * 68];
  __shared__ __align__(16) float wl[32 * 68];
  int b0 = blockIdx.x * 64, o0 = blockIdx.y * 64;
  int oq = threadIdx.x & 15, bq = threadIdx.x >> 4;
  f4 acc[4];
  #pragma unroll
  for (int i2 = 0; i2 < 4; ++i2) acc[i2] = (f4){0.f, 0.f, 0.f, 0.f};
  for (int cb = 0; cb < 32; ++cb) {
    if (cb) __syncthreads();
    for (int i = threadIdx.x; i < 2048; i += 256) {
      int c = i & 31, bb = i >> 5;
      il[c * 68 + bb] = (b0 + bb < NB) ? in[(b0 + bb) * 1024 + cb * 32 + c] : 0.f;
    }
    for (int i = threadIdx.x; i < 2048; i += 256) {
      int c = i & 31, ol = i >> 5;
      wl[c * 68 + ol] = (o0 + ol < ON) ? Wt[(o0 + ol) * 1024 + cb * 32 + c] : 0.f;
    }
    __syncthreads();
    #pragma unroll
    for (int c = 0; c < 32; ++c) {
      f4 wv = *(const f4*)&wl[c * 68 + oq * 4];
      f4 iv = *(const f4*)&il[c * 68 + bq * 4];
      acc[0] += wv.x * iv; acc[1] += wv.y * iv; acc[2] += wv.z * iv; acc[3] += wv.w * iv;
    }
  }
  #pragma unroll
  for (int i2 = 0; i2 < 4; ++i2) {
    int o = o0 + oq * 4 + i2;
    if (o >= ON) continue;
    float A = 1.f, Dv = 0.f;
    if (FUSE) { float a = q0[o] * rsqrtf(q3[o] + 1e-5f); A = a; Dv = q1[o] - q2[o] * a; }
    else { Dv = q0[o]; }
    #pragma unroll
    for (int jj = 0; jj < 4; ++jj) {
      int bb = b0 + bq * 4 + jj;
      if (bb < NB) {
        float v = acc[i2][jj];
        if (FUSE) { v = A * v + Dv; v = (v >= 0.f) ? v : 0.2f * v; }
        else { v = v + Dv; }
        out[(size_t)bb * ostride + o] = v;
      }
    }
  }
}

extern "C" void kernel_launch(void* const* d_in, const int* in_sizes, int n_in,
                              void* d_out, int out_size, void* d_ws, size_t ws_size,
                              hipStream_t stream) {
  const float* input = (const float*)d_in[0];
  const float* W1 = (const float*)d_in[1];
  const float* W2 = (const float*)d_in[2];
  const float* W3 = (const float*)d_in[3];
  const float* W4 = (const float*)d_in[4];
  const float* W5 = (const float*)d_in[5];
  const float* g5 = (const float*)d_in[6];
  const float* b5 = (const float*)d_in[7];
  const float* m5 = (const float*)d_in[8];
  const float* v5 = (const float*)d_in[9];
  const float* Wl1 = (const float*)d_in[10];
  const float* g6 = (const float*)d_in[11];
  const float* b6 = (const float*)d_in[12];
  const float* m6 = (const float*)d_in[13];
  const float* v6 = (const float*)d_in[14];
  const float* Wl2 = (const float*)d_in[15];
  const float* bl2 = (const float*)d_in[16];

  float* w = (float*)d_ws;
  // Tiered layouts. Per-64ch h/l chunk pair: 2 x 759*224*72 shorts.
  // need(NCH) = 4*(25,229,684 + 12,241,152*NCH) bytes.
  int NCH = 0;
  if (ws_size >= 4ull * (25229684ull + 12241152ull * 3)) NCH = 3;       // x3+x4 pre-split, 247.9 MB
  else if (ws_size >= 4ull * (25229684ull + 12241152ull * 2)) NCH = 2;  // x4 pre-split, 198.9 MB

  float *x0, *xc, *p, *z; int* idxb;
  unsigned short *wh, *wlo, *xh, *xlo;
  int chs, csplit, split_cb;
  if (NCH > 0) {
    x0 = w;                               //      500,940
    xc = x0 + 500940;                     //   21,373,440 (759*128*220 fp32: x1|x2|x3)
    p  = xc + 21373440;                   //      777,216
    z  = p  + 777216;                     //      777,216
    idxb = (int*)(z + 777216);            //    1,669,800 ints
    wh  = (unsigned short*)(w + 25098612);
    wlo = wh + 131072;
    xh  = wlo + 131072;                   //   NCH*12,241,152 shorts
    xlo = xh + (size_t)NCH * 12241152;
    chs = 128; csplit = 256 - 64 * NCH; split_cb = 4 - NCH;
  } else {
    x0 = w;
    xc = x0 + 500940;                     //   42,746,880 (759*256*220 fp32)
    p  = xc + 42746880;
    z  = p  + 777216;
    idxb = (int*)(z + 777216);
    wh  = (unsigned short*)(w + 46472052);
    wlo = wh + 131072;
    xh = wlo; xlo = wlo;                  // unused
    chs = 256; csplit = 256; split_cb = 4;
  }
  int ldxc = chs * NPT;

  k_transpose<<<1957, 256, 0, stream>>>(input, x0);
  k_w5split<<<512, 256, 0, stream>>>(W5, wh, wlo);

  k_knn3<<<759, 256, 0, stream>>>(x0, 3 * NPT, idxb);

  if (NCH == 3) {
    k_conv_fused<3, 1, false, true><<<759, 512, 0, stream>>>(x0, 3 * NPT, W1, idxb, xc, chs, xh, xlo, 0, csplit, NCH);
    k_knn_mfma<32><<<759, 512, 0, stream>>>(xc, ldxc, idxb);
    k_conv_fused<32, 1, false, true><<<759, 512, 0, stream>>>(xc, ldxc, W2, idxb, xc + 32 * NPT, chs, xh, xlo, 32, csplit, NCH);
    k_knn_mfma<32><<<759, 512, 0, stream>>>(xc + 32 * NPT, ldxc, idxb);
    k_conv_fused<32, 2, true, true><<<1520, 512, 0, stream>>>(xc + 32 * NPT, ldxc, W3, idxb, xc + 64 * NPT, chs, xh, xlo, 64, csplit, NCH);
    k_knn_mfma<64><<<759, 512, 0, stream>>>(xc + 64 * NPT, ldxc, idxb);
    k_conv_fused<64, 4, true, false><<<3040, 512, 0, stream>>>(xc + 64 * NPT, ldxc, W4, idxb, xc, 0, xh, xlo, 128, csplit, NCH);
  } else if (NCH == 2) {
    k_conv_fused<3, 1, false, true><<<759, 512, 0, stream>>>(x0, 3 * NPT, W1, idxb, xc, chs, xh, xlo, 0, csplit, NCH);
    k_knn_mfma<32><<<759, 512, 0, stream>>>(xc, ldxc, idxb);
    k_conv_fused<32, 1, false, true><<<759, 512, 0, stream>>>(xc, ldxc, W2, idxb, xc + 32 * NPT, chs, xh, xlo, 32, csplit, NCH);
    k_knn_mfma<32><<<759, 512, 0, stream>>>(xc + 32 * NPT, ldxc, idxb);
    k_conv_fused<32, 2, false, true><<<1520, 512, 0, stream>>>(xc + 32 * NPT, ldxc, W3, idxb, xc + 64 * NPT, chs, xh, xlo, 64, csplit, NCH);
    k_knn_mfma<64><<<759, 512, 0, stream>>>(xc + 64 * NPT, ldxc, idxb);
    k_conv_fused<64, 4, true, false><<<3040, 512, 0, stream>>>(xc + 64 * NPT, ldxc, W4, idxb, xc, 0, xh, xlo, 128, csplit, NCH);
  } else {
    k_conv_fused<3, 1, false, true><<<759, 512, 0, stream>>>(x0, 3 * NPT, W1, idxb, xc, chs, xh, xlo, 0, csplit, NCH);
    k_knn_mfma<32><<<759, 512, 0, stream>>>(xc, ldxc, idxb);
    k_conv_fused<32, 1, false, true><<<759, 512, 0, stream>>>(xc, ldxc, W2, idxb, xc + 32 * NPT, chs, xh, xlo, 32, csplit, NCH);
    k_knn_mfma<32><<<759, 512, 0, stream>>>(xc + 32 * NPT, ldxc, idxb);
    k_conv_fused<32, 2, false, true><<<1520, 512, 0, stream>>>(xc + 32 * NPT, ldxc, W3, idxb, xc + 64 * NPT, chs, xh, xlo, 64, csplit, NCH);
    k_knn_mfma<64><<<759, 512, 0, stream>>>(xc + 64 * NPT, ldxc, idxb);
    k_conv_fused<64, 4, false, true><<<3040, 512, 0, stream>>>(xc + 64 * NPT, ldxc, W4, idxb, xc + 128 * NPT, chs, xh, xlo, 128, csplit, NCH);
  }

  k_w5_mfma<<<3040, 256, 0, stream>>>(xc, chs, xh, xlo, split_cb, NCH, wh, wlo, g5, b5, m5, v5, p);

  k_fc<1024, true><<<dim3(12, 16), 256, 0, stream>>>(p, Wl1, g6, b6, m6, v6, z, 1024);
  k_fc<380, false><<<dim3(12, 6), 256, 0, stream>>>(z, Wl2, bl2, bl2, bl2, bl2, (float*)d_out, 380);
}

// Round 15
// 1492.865 us; speedup vs baseline: 1.1465x; 1.0573x over previous
//
#include <hip/hip_runtime.h>
#include <math.h>

#define NB 759
#define NPT 220
#define KNN 10
#define XCCH 256
#define LDXC (XCCH * NPT)
#define KP 72

typedef float f4 __attribute__((ext_vector_type(4)));
typedef float f16v __attribute__((ext_vector_type(16)));
typedef short bf8v __attribute__((ext_vector_type(8)));   // 8 bf16 in 4 VGPRs
typedef unsigned u4v __attribute__((ext_vector_type(4))); // 16B copy unit

// ---- bf16 split helpers (RNE). h+m+l reconstructs fp32 ~exactly (24=3x8 bits).
__device__ inline unsigned short bfh(float x) {
  unsigned u = __float_as_uint(x);
  unsigned r = u + 0x7FFFu + ((u >> 16) & 1u);
  return (unsigned short)(r >> 16);
}
__device__ inline float bff(unsigned short h) {
  return __uint_as_float(((unsigned)h) << 16);
}
__device__ inline void bfsplit(float x, unsigned short& h, unsigned short& l) {
  h = bfh(x);
  l = bfh(x - bff(h));
}

// input (B,N,3) -> x0 (B,3,N)
__global__ __launch_bounds__(256) void k_transpose(const float* __restrict__ in, float* __restrict__ x0) {
  int i = blockIdx.x * 256 + threadIdx.x;
  if (i >= NB * 3 * NPT) return;
  int n = i % NPT; int t = i / NPT; int c = t % 3; int b = t / 3;
  x0[i] = in[(b * NPT + n) * 3 + c];
}

// W5 (512x256 fp32) -> Wh, Wl (bf16)
__global__ __launch_bounds__(256) void k_w5split(const float* __restrict__ W5,
    unsigned short* __restrict__ Wh, unsigned short* __restrict__ Wl) {
  int i = blockIdx.x * 256 + threadIdx.x;
  if (i >= 512 * 256) return;
  bfsplit(W5[i], Wh[i], Wl[i]);
}

__device__ inline void topk_insert(float d, int m, float* tv, int* ti) {
  if (d > tv[KNN - 1]) {      // strict >: ties keep earlier index (matches lax.top_k set)
    tv[KNN - 1] = d; ti[KNN - 1] = m;
    #pragma unroll
    for (int j = KNN - 1; j >= 1; --j) {
      if (tv[j] > tv[j - 1]) {
        float tf = tv[j - 1]; tv[j - 1] = tv[j]; tv[j] = tf;
        int tq = ti[j - 1]; ti[j - 1] = ti[j]; ti[j] = tq;
      } else break;
    }
  }
}

// kNN for C=3: cheap VALU version
__global__ __launch_bounds__(256) void k_knn3(const float* __restrict__ x, int ldb,
                                              int* __restrict__ idxout) {
  __shared__ __align__(16) float xl[NPT * 4];
  __shared__ float xx[NPT];
  int b = blockIdx.x;
  const float* xb = x + (size_t)b * ldb;
  for (int i = threadIdx.x; i < NPT; i += 256) {
    f4 v; v.x = xb[i]; v.y = xb[NPT + i]; v.z = xb[2 * NPT + i]; v.w = 0.f;
    *(f4*)&xl[i * 4] = v;
    xx[i] = v.x * v.x + v.y * v.y + v.z * v.z;
  }
  __syncthreads();
  int n = threadIdx.x;
  if (n >= NPT) return;
  f4 xn = *(const f4*)&xl[n * 4];
  float xxn = xx[n];
  float tv[KNN]; int ti[KNN];
  #pragma unroll
  for (int k = 0; k < KNN; ++k) { tv[k] = -1e30f; ti[k] = 0; }
  for (int m = 0; m < NPT; ++m) {
    f4 v = *(const f4*)&xl[m * 4];
    float dot = xn.x * v.x + xn.y * v.y + xn.z * v.z;
    topk_insert(2.f * dot - xxn - xx[m], m, tv, ti);
  }
  int* ib = idxout + ((size_t)b * NPT + n) * KNN;
  #pragma unroll
  for (int k = 0; k < KNN; ++k) ib[k] = ti[k];
}

// kNN via MFMA Gram matrix, 3-way bf16 split (6 products ~ fp32-exact).
template<int C>
__global__ __launch_bounds__(512) void k_knn_mfma(const float* __restrict__ x, int ldb,
                                                  int* __restrict__ idxout) {
  constexpr int KPG = C + 8;
  constexpr int SW = (C / 16) - 1;
  __shared__ __align__(16) unsigned short XH[224 * KPG];
  __shared__ __align__(16) unsigned short XM[224 * KPG];
  __shared__ __align__(16) unsigned short XL[224 * KPG];
  __shared__ float xx[224];
  int b = blockIdx.x;
  const float* xb = x + (size_t)b * ldb;
  for (int i = threadIdx.x; i < C * 224; i += 512) {
    int c = i / 224, m = i - c * 224;
    float v = (m < NPT) ? xb[c * NPT + m] : 0.f;
    unsigned short h = bfh(v);
    float r1 = v - bff(h);
    unsigned short mm = bfh(r1);
    unsigned short l = bfh(r1 - bff(mm));
    int cs = c ^ ((m & SW) << 4);
    XH[m * KPG + cs] = h; XM[m * KPG + cs] = mm; XL[m * KPG + cs] = l;
  }
  for (int m = threadIdx.x; m < 224; m += 512) {
    float s = 0.f;
    if (m < NPT) {
      for (int c = 0; c < C; ++c) { float v = xb[c * NPT + m]; s += v * v; }
    } else s = 1e30f;
    xx[m] = s;
  }
  __syncthreads();
  int w = threadIdx.x >> 6;
  int lane = threadIdx.x & 63;
  int lc = lane & 31, hi = lane >> 5;
  float tv[KNN]; int ti[KNN];
  #pragma unroll
  for (int k = 0; k < KNN; ++k) { tv[k] = -1e30f; ti[k] = 0; }
  if (w < 7) {
    int n = w * 32 + lc;
    f16v acc[7];
    #pragma unroll
    for (int mt = 0; mt < 7; ++mt)
      #pragma unroll
      for (int i = 0; i < 16; ++i) acc[mt][i] = 0.f;
    #pragma unroll
    for (int ks = 0; ks < C / 16; ++ks) {
      int kb = ks * 16 + hi * 8;
      int nsw = kb ^ ((n & SW) << 4);
      bf8v bh = *(const bf8v*)&XH[n * KPG + nsw];
      bf8v bm = *(const bf8v*)&XM[n * KPG + nsw];
      bf8v bl = *(const bf8v*)&XL[n * KPG + nsw];
      #pragma unroll
      for (int mt = 0; mt < 7; ++mt) {
        int mr = mt * 32 + lc;
        int msw = kb ^ ((mr & SW) << 4);
        bf8v ah = *(const bf8v*)&XH[mr * KPG + msw];
        bf8v am = *(const bf8v*)&XM[mr * KPG + msw];
        bf8v al = *(const bf8v*)&XL[mr * KPG + msw];
        acc[mt] = __builtin_amdgcn_mfma_f32_32x32x16_bf16(ah, bh, acc[mt], 0, 0, 0);
        acc[mt] = __builtin_amdgcn_mfma_f32_32x32x16_bf16(am, bh, acc[mt], 0, 0, 0);
        acc[mt] = __builtin_amdgcn_mfma_f32_32x32x16_bf16(ah, bm, acc[mt], 0, 0, 0);
        acc[mt] = __builtin_amdgcn_mfma_f32_32x32x16_bf16(am, bm, acc[mt], 0, 0, 0);
        acc[mt] = __builtin_amdgcn_mfma_f32_32x32x16_bf16(al, bh, acc[mt], 0, 0, 0);
        acc[mt] = __builtin_amdgcn_mfma_f32_32x32x16_bf16(ah, bl, acc[mt], 0, 0, 0);
      }
    }
    float xxn = xx[n];
    #pragma unroll
    for (int mt = 0; mt < 7; ++mt)
      #pragma unroll
      for (int i = 0; i < 16; ++i) {
        int m = mt * 32 + (i & 3) + 8 * (i >> 2) + 4 * hi;
        float d = 2.f * acc[mt][i] - xx[m] - xxn;
        topk_insert(d, m, tv, ti);
      }
  }
  __syncthreads();
  float* LV = (float*)XH;
  int* LI = (int*)XM;
  if (w < 7) {
    int slot = (w * 64 + lane) * KNN;
    #pragma unroll
    for (int k = 0; k < KNN; ++k) { LV[slot + k] = tv[k]; LI[slot + k] = ti[k]; }
  }
  __syncthreads();
  if (w < 7 && hi == 0) {
    int n = w * 32 + lc;
    if (n < NPT) {
      int sa = (w * 64 + lane) * KNN, sb = sa + 32 * KNN;
      int a = 0, bq = 0;
      int* ob = idxout + ((size_t)b * NPT + n) * KNN;
      #pragma unroll
      for (int k = 0; k < KNN; ++k) {
        float va = LV[sa + a], vb = LV[sb + bq];
        int ia = LI[sa + a], ic = LI[sb + bq];
        bool ta = (va > vb) || (va == vb && ia < ic);
        ob[k] = ta ? ia : ic;
        if (ta) ++a; else ++bq;
      }
    }
  }
}

// Fused edge conv — 512 threads. R15: DBS=225 (225%32==1) so db-row bank
// depends on ol+idx -> the 4 cs-lanes of the image gather land on distinct
// banks (was guaranteed 4-way with 224). GEMM writeback becomes scalar b32
// stores (rows no longer 16B-aligned); ~2-way banked, once per element.
// Pure layout change -> bitwise-identical output.
template<int CIN, int OG, bool WBF16, bool WF32>
__global__ __launch_bounds__(512, 4) void k_conv_fused(const float* __restrict__ x, int ldb,
    const float* __restrict__ W, const int* __restrict__ idxb, float* __restrict__ xout, int ldo,
    unsigned short* __restrict__ xch, unsigned short* __restrict__ xcl, int cbase,
    int csplit, int nch) {
  constexpr int NPAD = 224;
  constexpr int DBS = 225;
  constexpr int REGION = 64 * DBS;
  __shared__ __align__(16) float smem[REGION + CIN * 64];
  __shared__ unsigned short idxl[NPT * KNN];
  float* xl = smem;
  float* db = smem;
  float* wl = smem + REGION;
  int d = blockIdx.x;
  int b, og;
  if (OG == 4)      { b = (d & 7) * 95 + (d >> 5); og = (d >> 3) & 3; }
  else if (OG == 2) { b = (d & 7) * 95 + (d >> 4); og = (d >> 3) & 1; }
  else              { b = d; og = 0; }
  if (b >= NB) return;
  const float* xb = x + (size_t)b * ldb;
  for (int i = threadIdx.x; i < CIN * NPAD; i += 512) {
    int c = i / NPAD, n = i - c * NPAD;
    xl[i] = (n < NPT) ? xb[c * NPT + n] : 0.f;
  }
  for (int i = threadIdx.x; i < 64 * CIN; i += 512) {
    int rl = i & 63, c = i >> 6;
    int o = og * 32 + (rl & 31);
    float wv = (rl < 32) ? W[o * 2 * CIN + c]
                         : (W[o * 2 * CIN + CIN + c] - W[o * 2 * CIN + c]);
    wl[c * 64 + rl] = wv;
  }
  for (int i = threadIdx.x; i < NPT * KNN; i += 512)
    idxl[i] = (unsigned short)idxb[(size_t)b * NPT * KNN + i];
  __syncthreads();
  int rq = threadIdx.x & 15, nq = threadIdx.x >> 4;   // nq in [0,32)
  int gv[2]; bool gok[2];
  #pragma unroll
  for (int j = 0; j < 2; ++j) { int g = nq + j * 32; gok[j] = g < 55; gv[j] = (g < 55 ? g : 54) * 4; }
  f4 acc[2][4];
  #pragma unroll
  for (int j = 0; j < 2; ++j)
    #pragma unroll
    for (int i2 = 0; i2 < 4; ++i2) acc[j][i2] = (f4){0.f, 0.f, 0.f, 0.f};
  #pragma unroll 2
  for (int c = 0; c < CIN; ++c) {
    f4 wv = *(const f4*)&wl[c * 64 + rq * 4];
    #pragma unroll
    for (int j = 0; j < 2; ++j) {
      f4 xv = *(const f4*)&xl[c * NPAD + gv[j]];
      acc[j][0] += wv.x * xv; acc[j][1] += wv.y * xv;
      acc[j][2] += wv.z * xv; acc[j][3] += wv.w * xv;
    }
  }
  __syncthreads();
  #pragma unroll
  for (int j = 0; j < 2; ++j) {
    if (gok[j]) {
      #pragma unroll
      for (int i2 = 0; i2 < 4; ++i2) {
        #pragma unroll
        for (int q = 0; q < 4; ++q)
          db[(rq * 4 + i2) * DBS + gv[j] + q] = acc[j][i2][q];
      }
    }
  }
  __syncthreads();
  int o0 = og * 32;
  if (WF32) {
    for (int i = threadIdx.x; i < 32 * NPT; i += 512) {
      int ol = i / NPT, n = i - ol * NPT;
      const float* drow = &db[ol * DBS];
      const unsigned short* ib = &idxl[n * KNN];
      float mx = -1e30f;
      #pragma unroll
      for (int k = 0; k < KNN; ++k) mx = fmaxf(mx, drow[ib[k]]);
      float v = mx + db[(32 + ol) * DBS + n];
      v = (v >= 0.f) ? v : 0.2f * v;
      xout[((size_t)b * ldo + o0 + ol) * NPT + n] = v;
    }
  }
  if (WBF16) {
    // i = n*4 + cs: lanes (cs fastest) -> 4 lanes cover one 64B row segment
    for (int i = threadIdx.x; i < 224 * 4; i += 512) {
      int n = i >> 2, cs = i & 3;
      unsigned short hs[8], ls[8];
      if (n < NPT) {
        const unsigned short* ib = &idxl[n * KNN];
        unsigned short ixr[KNN];
        #pragma unroll
        for (int k = 0; k < KNN; ++k) ixr[k] = ib[k];
        #pragma unroll
        for (int j = 0; j < 8; ++j) {
          int ol = cs * 8 + j;
          const float* drow = &db[ol * DBS];
          float mx = -1e30f;
          #pragma unroll
          for (int k = 0; k < KNN; ++k) mx = fmaxf(mx, drow[ixr[k]]);
          float v = mx + db[(32 + ol) * DBS + n];
          v = (v >= 0.f) ? v : 0.2f * v;
          bfsplit(v, hs[j], ls[j]);
        }
      } else {
        #pragma unroll
        for (int j = 0; j < 8; ++j) { hs[j] = 0; ls[j] = 0; }
      }
      int cc0 = cbase + o0 + cs * 8 - csplit;
      size_t off = (((size_t)b * nch + (cc0 >> 6)) * 224 + n) * (size_t)KP + (cc0 & 63);
      u4v hv, lv;
      #pragma unroll
      for (int q = 0; q < 4; ++q) {
        hv[q] = (unsigned)hs[2 * q] | ((unsigned)hs[2 * q + 1] << 16);
        lv[q] = (unsigned)ls[2 * q] | ((unsigned)ls[2 * q + 1] << 16);
      }
      *(u4v*)&xch[off] = hv;
      *(u4v*)&xcl[off] = lv;
    }
  }
}

// W5 GEMM via split-bf16 MFMA (R6 structure). Hybrid staging: chunks
// cb < split_cb split inline from fp32 xc; cb >= split_cb are contiguous
// memcpys from the conv-emitted h/l image. split_cb=4 == exact fallback.
__global__ __launch_bounds__(256) void k_w5_mfma(const float* __restrict__ xc, int chs,
    const unsigned short* __restrict__ xh, const unsigned short* __restrict__ xlo,
    int split_cb, int nch,
    const unsigned short* __restrict__ Wh, const unsigned short* __restrict__ Wl,
    const float* __restrict__ g5, const float* __restrict__ b5, const float* __restrict__ m5,
    const float* __restrict__ v5, float* __restrict__ p) {
  __shared__ __align__(16) unsigned short XH[224 * KP];
  __shared__ __align__(16) unsigned short XL[224 * KP];
  int d = blockIdx.x;
  int b = (d & 7) * 95 + (d >> 5);
  int rg = (d >> 3) & 3;
  if (b >= NB) return;
  int lane = threadIdx.x & 63, w = threadIdx.x >> 6;
  f16v acc[7];
  #pragma unroll
  for (int t = 0; t < 7; ++t)
    #pragma unroll
    for (int i = 0; i < 16; ++i) acc[t][i] = 0.f;

  int r = rg * 128 + w * 32 + (lane & 31);
  int khalf = (lane >> 5) * 8;

  for (int cb = 0; cb < 4; ++cb) {
    if (cb) __syncthreads();
    if (cb < split_cb) {
      // inline split from fp32 xc (identical to fallback)
      for (int i = threadIdx.x; i < 32 * NPT; i += 256) {
        int cp = i / NPT;
        int n = i - cp * NPT;
        int c0 = cp * 2;
        const float* src = &xc[((size_t)b * chs + cb * 64 + c0) * NPT + n];
        float x0 = src[0];
        float x1 = src[NPT];
        unsigned short h0, l0, h1, l1;
        bfsplit(x0, h0, l0); bfsplit(x1, h1, l1);
        ((unsigned*)XH)[(n * KP + c0) >> 1] = (unsigned)h0 | ((unsigned)h1 << 16);
        ((unsigned*)XL)[(n * KP + c0) >> 1] = (unsigned)l0 | ((unsigned)l1 << 16);
      }
      for (int i = threadIdx.x; i < 4 * 32; i += 256) {
        int n = NPT + (i >> 5); int cd = i & 31;
        ((unsigned*)XH)[n * (KP / 2) + cd] = 0u;
        ((unsigned*)XL)[n * (KP / 2) + cd] = 0u;
      }
    } else {
      // contiguous memcpy: global layout == LDS layout [224][KP]
      int q = cb - split_cb;
      const u4v* sH = (const u4v*)(xh + (((size_t)b * nch + q) * 224) * KP);
      const u4v* sL = (const u4v*)(xlo + (((size_t)b * nch + q) * 224) * KP);
      u4v* dH = (u4v*)XH;
      u4v* dL = (u4v*)XL;
      for (int i = threadIdx.x; i < 224 * KP / 8; i += 256) {
        dH[i] = sH[i];
        dL[i] = sL[i];
      }
    }
    __syncthreads();
    #pragma unroll
    for (int ks = 0; ks < 4; ++ks) {
      int kg = cb * 64 + ks * 16 + khalf;
      int kl = ks * 16 + khalf;
      bf8v ah = *(const bf8v*)&Wh[(size_t)r * 256 + kg];
      bf8v al = *(const bf8v*)&Wl[(size_t)r * 256 + kg];
      #pragma unroll
      for (int t = 0; t < 7; ++t) {
        int col = t * 32 + (lane & 31);
        bf8v bh = *(const bf8v*)&XH[col * KP + kl];
        bf8v bl = *(const bf8v*)&XL[col * KP + kl];
        acc[t] = __builtin_amdgcn_mfma_f32_32x32x16_bf16(ah, bh, acc[t], 0, 0, 0);
        acc[t] = __builtin_amdgcn_mfma_f32_32x32x16_bf16(al, bh, acc[t], 0, 0, 0);
        acc[t] = __builtin_amdgcn_mfma_f32_32x32x16_bf16(ah, bl, acc[t], 0, 0, 0);
      }
    }
  }
  int rbase = rg * 128 + w * 32 + 4 * (lane >> 5);
  int lc = lane & 31;
  #pragma unroll
  for (int i = 0; i < 16; ++i) {
    int row = rbase + (i & 3) + 8 * (i >> 2);
    float a = g5[row] * rsqrtf(v5[row] + 1e-5f);
    float dq = b5[row] - m5[row] * a;
    float mx = -1e30f, sm = 0.f;
    #pragma unroll
    for (int t = 0; t < 7; ++t) {
      bool valid = (t < 6) || (lc < 28);
      float hv = a * acc[t][i] + dq;
      float lv = (hv >= 0.f) ? hv : 0.2f * hv;
      if (valid) { mx = fmaxf(mx, lv); sm += lv; }
    }
    #pragma unroll
    for (int m_ = 1; m_ <= 16; m_ <<= 1) {
      mx = fmaxf(mx, __shfl_xor(mx, m_));
      sm += __shfl_xor(sm, m_);
    }
    if (lc == 0) {
      p[(size_t)b * 1024 + row] = mx;
      p[(size_t)b * 1024 + 512 + row] = sm * (1.f / NPT);
    }
  }
}

// out[b][o] = in[b][:] . Wt[o][:]  (+ bn+leaky | + bias)
template<int ON, bool FUSE>
__global__ __launch_bounds__(256) void k_fc(const float* __restrict__ in, const float* __restrict__ Wt,
    const float* __restrict__ q0, const float* __restrict__ q1, const float* __restrict__ q2,
    const float* __restrict__ q3, float* __restrict__ out, int ostride) {
  __shared__ __align__(16) float il[32 * 68];
  __shared__ __align__(16) float wl[32 * 68];
  int b0 = blockIdx.x * 64, o0 = blockIdx.y * 64;
  int oq = threadIdx.x & 15, bq = threadIdx.x >> 4;
  f4 acc[4];
  #pragma unroll
  for (int i2 = 0; i2 < 4; ++i2) acc[i2] = (f4){0.f, 0.f, 0.f, 0.f};
  for (int cb = 0; cb < 32; ++cb) {
    if (cb) __syncthreads();
    for (int i = threadIdx.x; i < 2048; i += 256) {
      int c = i & 31, bb = i >> 5;
      il[c * 68 + bb] = (b0 + bb < NB) ? in[(b0 + bb) * 1024 + cb * 32 + c] : 0.f;
    }
    for (int i = threadIdx.x; i < 2048; i += 256) {
      int c = i & 31, ol = i >> 5;
      wl[c * 68 + ol] = (o0 + ol < ON) ? Wt[(o0 + ol) * 1024 + cb * 32 + c] : 0.f;
    }
    __syncthreads();
    #pragma unroll
    for (int c = 0; c < 32; ++c) {
      f4 wv = *(const f4*)&wl[c * 68 + oq * 4];
      f4 iv = *(const f4*)&il[c * 68 + bq * 4];
      acc[0] += wv.x * iv; acc[1] += wv.y * iv; acc[2] += wv.z * iv; acc[3] += wv.w * iv;
    }
  }
  #pragma unroll
  for (int i2 = 0; i2 < 4; ++i2) {
    int o = o0 + oq * 4 + i2;
    if (o >= ON) continue;
    float A = 1.f, Dv = 0.f;
    if (FUSE) { float a = q0[o] * rsqrtf(q3[o] + 1e-5f); A = a; Dv = q1[o] - q2[o] * a; }
    else { Dv = q0[o]; }
    #pragma unroll
    for (int jj = 0; jj < 4; ++jj) {
      int bb = b0 + bq * 4 + jj;
      if (bb < NB) {
        float v = acc[i2][jj];
        if (FUSE) { v = A * v + Dv; v = (v >= 0.f) ? v : 0.2f * v; }
        else { v = v + Dv; }
        out[(size_t)bb * ostride + o] = v;
      }
    }
  }
}

extern "C" void kernel_launch(void* const* d_in, const int* in_sizes, int n_in,
                              void* d_out, int out_size, void* d_ws, size_t ws_size,
                              hipStream_t stream) {
  const float* input = (const float*)d_in[0];
  const float* W1 = (const float*)d_in[1];
  const float* W2 = (const float*)d_in[2];
  const float* W3 = (const float*)d_in[3];
  const float* W4 = (const float*)d_in[4];
  const float* W5 = (const float*)d_in[5];
  const float* g5 = (const float*)d_in[6];
  const float* b5 = (const float*)d_in[7];
  const float* m5 = (const float*)d_in[8];
  const float* v5 = (const float*)d_in[9];
  const float* Wl1 = (const float*)d_in[10];
  const float* g6 = (const float*)d_in[11];
  const float* b6 = (const float*)d_in[12];
  const float* m6 = (const float*)d_in[13];
  const float* v6 = (const float*)d_in[14];
  const float* Wl2 = (const float*)d_in[15];
  const float* bl2 = (const float*)d_in[16];

  float* w = (float*)d_ws;
  // Tiered layouts. Per-64ch h/l chunk pair: 2 x 759*224*72 shorts.
  // need(NCH) = 4*(25,229,684 + 12,241,152*NCH) bytes.
  int NCH = 0;
  if (ws_size >= 4ull * (25229684ull + 12241152ull * 3)) NCH = 3;       // x3+x4 pre-split, 247.9 MB
  else if (ws_size >= 4ull * (25229684ull + 12241152ull * 2)) NCH = 2;  // x4 pre-split, 198.9 MB

  float *x0, *xc, *p, *z; int* idxb;
  unsigned short *wh, *wlo, *xh, *xlo;
  int chs, csplit, split_cb;
  if (NCH > 0) {
    x0 = w;                               //      500,940
    xc = x0 + 500940;                     //   21,373,440 (759*128*220 fp32: x1|x2|x3)
    p  = xc + 21373440;                   //      777,216
    z  = p  + 777216;                     //      777,216
    idxb = (int*)(z + 777216);            //    1,669,800 ints
    wh  = (unsigned short*)(w + 25098612);
    wlo = wh + 131072;
    xh  = wlo + 131072;                   //   NCH*12,241,152 shorts
    xlo = xh + (size_t)NCH * 12241152;
    chs = 128; csplit = 256 - 64 * NCH; split_cb = 4 - NCH;
  } else {
    x0 = w;
    xc = x0 + 500940;                     //   42,746,880 (759*256*220 fp32)
    p  = xc + 42746880;
    z  = p  + 777216;
    idxb = (int*)(z + 777216);
    wh  = (unsigned short*)(w + 46472052);
    wlo = wh + 131072;
    xh = wlo; xlo = wlo;                  // unused
    chs = 256; csplit = 256; split_cb = 4;
  }
  int ldxc = chs * NPT;

  k_transpose<<<1957, 256, 0, stream>>>(input, x0);
  k_w5split<<<512, 256, 0, stream>>>(W5, wh, wlo);

  k_knn3<<<759, 256, 0, stream>>>(x0, 3 * NPT, idxb);

  if (NCH == 3) {
    k_conv_fused<3, 1, false, true><<<759, 512, 0, stream>>>(x0, 3 * NPT, W1, idxb, xc, chs, xh, xlo, 0, csplit, NCH);
    k_knn_mfma<32><<<759, 512, 0, stream>>>(xc, ldxc, idxb);
    k_conv_fused<32, 1, false, true><<<759, 512, 0, stream>>>(xc, ldxc, W2, idxb, xc + 32 * NPT, chs, xh, xlo, 32, csplit, NCH);
    k_knn_mfma<32><<<759, 512, 0, stream>>>(xc + 32 * NPT, ldxc, idxb);
    k_conv_fused<32, 2, true, true><<<1520, 512, 0, stream>>>(xc + 32 * NPT, ldxc, W3, idxb, xc + 64 * NPT, chs, xh, xlo, 64, csplit, NCH);
    k_knn_mfma<64><<<759, 512, 0, stream>>>(xc + 64 * NPT, ldxc, idxb);
    k_conv_fused<64, 4, true, false><<<3040, 512, 0, stream>>>(xc + 64 * NPT, ldxc, W4, idxb, xc, 0, xh, xlo, 128, csplit, NCH);
  } else if (NCH == 2) {
    k_conv_fused<3, 1, false, true><<<759, 512, 0, stream>>>(x0, 3 * NPT, W1, idxb, xc, chs, xh, xlo, 0, csplit, NCH);
    k_knn_mfma<32><<<759, 512, 0, stream>>>(xc, ldxc, idxb);
    k_conv_fused<32, 1, false, true><<<759, 512, 0, stream>>>(xc, ldxc, W2, idxb, xc + 32 * NPT, chs, xh, xlo, 32, csplit, NCH);
    k_knn_mfma<32><<<759, 512, 0, stream>>>(xc + 32 * NPT, ldxc, idxb);
    k_conv_fused<32, 2, false, true><<<1520, 512, 0, stream>>>(xc + 32 * NPT, ldxc, W3, idxb, xc + 64 * NPT, chs, xh, xlo, 64, csplit, NCH);
    k_knn_mfma<64><<<759, 512, 0, stream>>>(xc + 64 * NPT, ldxc, idxb);
    k_conv_fused<64, 4, true, false><<<3040, 512, 0, stream>>>(xc + 64 * NPT, ldxc, W4, idxb, xc, 0, xh, xlo, 128, csplit, NCH);
  } else {
    k_conv_fused<3, 1, false, true><<<759, 512, 0, stream>>>(x0, 3 * NPT, W1, idxb, xc, chs, xh, xlo, 0, csplit, NCH);
    k_knn_mfma<32><<<759, 512, 0, stream>>>(xc, ldxc, idxb);
    k_conv_fused<32, 1, false, true><<<759, 512, 0, stream>>>(xc, ldxc, W2, idxb, xc + 32 * NPT, chs, xh, xlo, 32, csplit, NCH);
    k_knn_mfma<32><<<759, 512, 0, stream>>>(xc + 32 * NPT, ldxc, idxb);
    k_conv_fused<32, 2, false, true><<<1520, 512, 0, stream>>>(xc + 32 * NPT, ldxc, W3, idxb, xc + 64 * NPT, chs, xh, xlo, 64, csplit, NCH);
    k_knn_mfma<64><<<759, 512, 0, stream>>>(xc + 64 * NPT, ldxc, idxb);
    k_conv_fused<64, 4, false, true><<<3040, 512, 0, stream>>>(xc + 64 * NPT, ldxc, W4, idxb, xc + 128 * NPT, chs, xh, xlo, 128, csplit, NCH);
  }

  k_w5_mfma<<<3040, 256, 0, stream>>>(xc, chs, xh, xlo, split_cb, NCH, wh, wlo, g5, b5, m5, v5, p);

  k_fc<1024, true><<<dim3(12, 16), 256, 0, stream>>>(p, Wl1, g6, b6, m6, v6, z, 1024);
  k_fc<380, false><<<dim3(12, 6), 256, 0, stream>>>(z, Wl2, bl2, bl2, bl2, bl2, (float*)d_out, 380);
}